// Round 7
// baseline (571.003 us; speedup 1.0000x reference)
//
#include <hip/hip_runtime.h>

#define B_    32768
#define IN_   512
#define HID_  256
#define OUT_  128
#define E_    16
#define CTX_  256
#define DEMO_ 16
#define GIN_  784

typedef __attribute__((ext_vector_type(8))) short short8;   // 8 bf16 = 4 VGPRs
typedef __attribute__((ext_vector_type(4))) float floatx4;  // MFMA C/D

// fp32 -> bf16 round-to-nearest-even
__device__ __forceinline__ short f2bf(float x){
  unsigned u = __builtin_bit_cast(unsigned, x);
  u += 0x7FFFu + ((u >> 16) & 1u);
  return (short)(u >> 16);
}

__device__ __forceinline__ short8 pack8(float4 a, float4 b){
  short8 r;
  r[0]=f2bf(a.x); r[1]=f2bf(a.y); r[2]=f2bf(a.z); r[3]=f2bf(a.w);
  r[4]=f2bf(b.x); r[5]=f2bf(b.y); r[6]=f2bf(b.z); r[7]=f2bf(b.w);
  return r;
}

__device__ __forceinline__ void load_lds16(const short* g, short* l){
  __builtin_amdgcn_global_load_lds((const __attribute__((address_space(1))) void*)g,
                                   (__attribute__((address_space(3))) void*)l,
                                   16, 0, 0);
}

// Counted-waitcnt + raw-barrier discipline (T3+T4).
#define VMCNT4()  asm volatile("s_waitcnt vmcnt(4)"  ::: "memory")
#define VMCNT2()  asm volatile("s_waitcnt vmcnt(2)"  ::: "memory")
#define VMCNT0()  asm volatile("s_waitcnt vmcnt(0)"  ::: "memory")
#define BAR() do{ asm volatile("" ::: "memory"); __builtin_amdgcn_s_barrier(); \
                  asm volatile("" ::: "memory"); }while(0)
// Retire this wave's LDS ops BEFORE signalling a buffer-reuse barrier.
#define LGKM0() do{ asm volatile("s_waitcnt lgkmcnt(0)" ::: "memory"); \
                    __builtin_amdgcn_sched_barrier(0); }while(0)

// Stage a 128x32 bf16 tile (8 KB) global->LDS, 2 instrs/thread.
// 16B-block swizzle keyed on row&3 (4 blocks/row): LDS[row][cb] = G[row][cb^(row&3)].
// Readers fetch block (kb ^ (row&3)). Same involution both sides (rule #21).
__device__ __forceinline__ void stage128x32(short* lds, const short* g, int gpitch, int tid){
  const int wvv = tid >> 6, ln = tid & 63;
  const int cb = ln & 3, rsub = ln >> 2;     // 4 16B-blocks/row, 16 rows per instr
  #pragma unroll
  for (int i = 0; i < 2; ++i){
    const int r0  = (wvv*2 + i)*16;          // wave-uniform row base
    const int row = r0 + rsub;
    const short* gp = g + (size_t)row*gpitch + ((cb ^ (row & 3)) << 3);
    load_lds16(gp, lds + r0*32);             // lane writes base + lane*16B (linear)
  }
}

// ---------------- fp32 -> bf16 convert (x, W1, W2) ----------------
__global__ void convert_kernel(const float* __restrict__ x, const float* __restrict__ w1,
                               const float* __restrict__ w2, short* __restrict__ xb,
                               short* __restrict__ w1b, short* __restrict__ w2b){
  const int N1 = B_*IN_, N2 = E_*HID_*IN_, N3 = E_*OUT_*HID_;
  const int total4 = (N1 + N2 + N3) >> 2;
  for (int i = blockIdx.x*blockDim.x + threadIdx.x; i < total4; i += gridDim.x*blockDim.x){
    int e4 = i << 2;
    const float* src; short* dst; int off;
    if (e4 < N1)            { src = x;  dst = xb;  off = e4; }
    else if (e4 < N1 + N2)  { src = w1; dst = w1b; off = e4 - N1; }
    else                    { src = w2; dst = w2b; off = e4 - (N1 + N2); }
    float4 v = *(const float4*)(src + off);
    *(short4*)(dst + off) = make_short4(f2bf(v.x), f2bf(v.y), f2bf(v.z), f2bf(v.w));
  }
}

// ---------------- gate via MFMA: softmax(cat(u,x,d) @ gW^T + gb) ----------------
__global__ __launch_bounds__(256)
void gate_kernel(const float* __restrict__ u, const short* __restrict__ xb,
                 const float* __restrict__ d, const float* __restrict__ gW,
                 const float* __restrict__ gb, float* __restrict__ wout){
  const int tid  = threadIdx.x;
  const int wave = tid >> 6, lane = tid & 63;
  const int l15  = lane & 15, quad = lane >> 4;
  const int row0 = blockIdx.x*64 + wave*16;
  const int rA   = row0 + l15;
  const int kq   = quad*8;

  floatx4 acc  = {0.f,0.f,0.f,0.f};
  floatx4 acc2 = {0.f,0.f,0.f,0.f};

  #pragma unroll
  for (int t = 0; t < 8; ++t){
    const float4 a0 = *(const float4*)&u[(size_t)rA*CTX_ + t*32 + kq];
    const float4 a1 = *(const float4*)&u[(size_t)rA*CTX_ + t*32 + kq + 4];
    const float4 b0 = *(const float4*)&gW[(size_t)l15*GIN_ + t*32 + kq];
    const float4 b1 = *(const float4*)&gW[(size_t)l15*GIN_ + t*32 + kq + 4];
    acc = __builtin_amdgcn_mfma_f32_16x16x32_bf16(pack8(a0,a1), pack8(b0,b1), acc, 0,0,0);
  }
  #pragma unroll
  for (int t = 0; t < 16; ++t){
    const short8 af = *(const short8*)&xb[(size_t)rA*IN_ + t*32 + kq];
    const float4 b0 = *(const float4*)&gW[(size_t)l15*GIN_ + 256 + t*32 + kq];
    const float4 b1 = *(const float4*)&gW[(size_t)l15*GIN_ + 256 + t*32 + kq + 4];
    acc2 = __builtin_amdgcn_mfma_f32_16x16x32_bf16(af, pack8(b0,b1), acc2, 0,0,0);
  }
  {
    short8 af = {0,0,0,0,0,0,0,0}, bf = {0,0,0,0,0,0,0,0};
    if (quad < 2){
      const float4 a0 = *(const float4*)&d[(size_t)rA*DEMO_ + kq];
      const float4 a1 = *(const float4*)&d[(size_t)rA*DEMO_ + kq + 4];
      const float4 b0 = *(const float4*)&gW[(size_t)l15*GIN_ + 768 + kq];
      const float4 b1 = *(const float4*)&gW[(size_t)l15*GIN_ + 768 + kq + 4];
      af = pack8(a0,a1); bf = pack8(b0,b1);
    }
    acc = __builtin_amdgcn_mfma_f32_16x16x32_bf16(af, bf, acc, 0,0,0);
  }

  const float bias = gb[l15];
  #pragma unroll
  for (int r = 0; r < 4; ++r){
    float v = acc[r] + acc2[r] + bias;
    float m = v;
    #pragma unroll
    for (int s = 1; s <= 8; s <<= 1) m = fmaxf(m, __shfl_xor(m, s));
    const float p = __expf(v - m);
    float ssum = p;
    #pragma unroll
    for (int s = 1; s <= 8; s <<= 1) ssum += __shfl_xor(ssum, s);
    wout[(size_t)(row0 + quad*4 + r)*E_ + l15] = p / ssum;
  }
}

// ---------------- fused MoE ----------------
// v8: 48 KB LDS -> 3 blocks/CU (was 64 KB / 2). K-chunks of 32, dbuf,
// counted vmcnt (VMCNT4 retires in-use chunk; next stays in flight across
// both barriers). W2: 4 x [128][32] chunks through a 16 KB dbuf.
// LDS 48 KB:
//   buf c [ (c&1)*16384, +16384 ): x tile 8K | w1 tile 8K
//   s_h  [0,32768): [128][128] row&7-keyed block-XOR (aliases both bufs)
//   s_w2 [32768,49152): 2 x [128][32] dbuf
__global__ __launch_bounds__(256, 3)
void moe_kernel(const short* __restrict__ xb, const short* __restrict__ w1b,
                const short* __restrict__ w2b, const float* __restrict__ gatew,
                const float* __restrict__ b1g, const float* __restrict__ b2g,
                float* __restrict__ out){
  __shared__ alignas(16) char smem[49152];
  short* s_h  = (short*)smem;
  short* s_w2 = (short*)(smem + 32768);

  const int tid  = threadIdx.x;
  const int wv   = tid >> 6;
  const int lane = tid & 63;
  const int l15  = lane & 15;
  const int hi2  = lane >> 4;
  const int r7   = l15 & 7;
  const int swb  = (hi2 ^ (l15 & 3)) << 3;   // 32-wide tile read block (shorts)
  const int h_off  = (wv >> 1) * 64;      // GEMM1: A rows (hidden)
  const int mb_off = (wv & 1) * 64;       // GEMM1: B cols (batch)
  const int m_off  = (wv >> 1) * 64;      // GEMM2: rows (batch)
  const int o_off  = (wv & 1) * 64;       // GEMM2: cols (out)
  const int blk_m0 = blockIdx.x * 128;
  const int eg = blockIdx.y;              // expert group 0..3

  floatx4 oacc[4][4];
  #pragma unroll
  for (int a = 0; a < 4; ++a)
    #pragma unroll
    for (int b = 0; b < 4; ++b) oacc[a][b] = floatx4{0.f,0.f,0.f,0.f};

  // bias-2 term for THIS block's 4 experts (linear over e -> distributable)
  #pragma unroll 1
  for (int ei = 0; ei < 4; ++ei){
    const int e = eg*4 + ei;
    float b2v[4];
    #pragma unroll
    for (int nt = 0; nt < 4; ++nt) b2v[nt] = b2g[e*OUT_ + o_off + nt*16 + l15];
    #pragma unroll
    for (int mt = 0; mt < 4; ++mt){
      #pragma unroll
      for (int r = 0; r < 4; ++r){
        const float wgt = gatew[(size_t)(blk_m0 + m_off + mt*16 + hi2*4 + r)*E_ + e];
        #pragma unroll
        for (int nt = 0; nt < 4; ++nt) oacc[mt][nt][r] += wgt * b2v[nt];
      }
    }
  }

  const short* xbase = xb + (size_t)blk_m0*IN_;

  #pragma unroll 1
  for (int ei = 0; ei < 4; ++ei){
    const int e = eg*4 + ei;
    #pragma unroll 1
    for (int half = 0; half < 2; ++half){
      const short* w1base = w1b + (size_t)(e*HID_ + half*128) * IN_;
      const short* w2base = w2b + (size_t)e*OUT_*HID_ + half*128;

      floatx4 g1[4][4];
      #pragma unroll
      for (int a = 0; a < 4; ++a)
        #pragma unroll
        for (int b = 0; b < 4; ++b) g1[a][b] = floatx4{0.f,0.f,0.f,0.f};

      // ---- GEMM1 prologue: chunk0 -> buf0 (prev iter's LGKM0+BAR made bufs safe)
      stage128x32((short*)smem,        xbase,  IN_, tid);
      stage128x32((short*)smem + 4096, w1base, IN_, tid);

      // ---- GEMM1: 16 chunks of K=32, dbuf, counted vmcnt
      // per kc: stage chunk kc+1 -> buf[(kc+1)&1] (holds chunk kc-1, retired at
      // kc-1's LGKM0+BAR); VMCNT4 retires chunk kc (queue: [c_kc(4), c_kc+1(4)]).
      #pragma unroll 1
      for (int kc = 0; kc < 16; ++kc){
        if (kc < 15){
          short* nb = (short*)(smem + ((kc + 1) & 1)*16384);
          stage128x32(nb,        xbase  + (kc+1)*32, IN_, tid);
          stage128x32(nb + 4096, w1base + (kc+1)*32, IN_, tid);
        } else {
          // kc==15: s_w2 free since prev GEMM2's LGKM0+BAR -> prestage W2 c0,c1
          stage128x32(s_w2,        w2base,      HID_, tid);
          stage128x32(s_w2 + 4096, w2base + 32, HID_, tid);
        }
        VMCNT4();                           // chunk kc landed (own); W2/next in flight
        BAR();                              // all waves' chunk kc landed
        const short* buf = (const short*)(smem + (kc & 1)*16384);
        __builtin_amdgcn_s_setprio(1);
        {
          short8 af[4];
          #pragma unroll
          for (int ht = 0; ht < 4; ++ht)
            af[ht] = *(const short8*)&buf[4096 + (h_off + ht*16 + l15)*32 + swb];
          #pragma unroll
          for (int mt = 0; mt < 4; ++mt){
            const short8 bf = *(const short8*)&buf[(mb_off + mt*16 + l15)*32 + swb];
            #pragma unroll
            for (int ht = 0; ht < 4; ++ht)
              g1[ht][mt] = __builtin_amdgcn_mfma_f32_16x16x32_bf16(af[ht], bf, g1[ht][mt], 0,0,0);
          }
        }
        __builtin_amdgcn_s_setprio(0);
        LGKM0();                            // this wave's ds_reads retired
        BAR();                              // -> buf safely reusable
      }

      // ---- epilogue: relu(+b1)*gate -> bf16 -> s_h (row&7-keyed block-XOR) ----
      // s_h = bufs; buf0 reads retired at kc=14's LGKM0+BAR, buf1 at kc=15's.
      // W2 c0,c1 DMA (-> s_w2, disjoint) proceeds underneath.
      {
        float4 b1v[4];
        #pragma unroll
        for (int ht = 0; ht < 4; ++ht)
          b1v[ht] = *(const float4*)&b1g[e*HID_ + half*128 + h_off + ht*16 + hi2*4];
        float wgt[4];
        #pragma unroll
        for (int mt = 0; mt < 4; ++mt)
          wgt[mt] = gatew[(size_t)(blk_m0 + mb_off + mt*16 + l15)*E_ + e];
        #pragma unroll
        for (int ht = 0; ht < 4; ++ht){
          const float b1r[4] = {b1v[ht].x, b1v[ht].y, b1v[ht].z, b1v[ht].w};
          const int hb3 = 2*ht + (hi2 >> 1);          // natural block in 64-short half
          #pragma unroll
          for (int mt = 0; mt < 4; ++mt){
            short4 pk;
            float v0 = fmaxf(g1[ht][mt][0] + b1r[0], 0.f) * wgt[mt];
            float v1 = fmaxf(g1[ht][mt][1] + b1r[1], 0.f) * wgt[mt];
            float v2 = fmaxf(g1[ht][mt][2] + b1r[2], 0.f) * wgt[mt];
            float v3 = fmaxf(g1[ht][mt][3] + b1r[3], 0.f) * wgt[mt];
            pk.x = f2bf(v0); pk.y = f2bf(v1); pk.z = f2bf(v2); pk.w = f2bf(v3);
            *(short4*)&s_h[(size_t)(mb_off + mt*16 + l15)*128 + h_off
                           + ((hb3 ^ r7) << 3) + (hi2 & 1)*4] = pk;
          }
        }
      }
      VMCNT0();                             // W2 c0,c1 landed (warm: issued at kc=15)
      asm volatile("s_waitcnt lgkmcnt(0)" ::: "memory");  // s_h writes done
      __builtin_amdgcn_sched_barrier(0);
      BAR();

      // ---- GEMM2: oacc += H[128,128] @ W2^T, 4 phases of K=32, s_w2 dbuf ----
      #pragma unroll 1
      for (int c = 0; c < 4; ++c){
        if (c == 1)      stage128x32(s_w2,        w2base + 64, HID_, tid); // c2->b0
        else if (c == 2){ stage128x32(s_w2 + 4096, w2base + 96, HID_, tid); // c3->b1
                          VMCNT2();         // queue [c2(2),c3(2)] -> retire c2
                          BAR(); }
        else if (c == 3){ VMCNT0();         // retire c3
                          BAR(); }
        // c==0,1: operand chunk already resident (pre-GEMM2 VMCNT0+BAR)
        const short* wb = s_w2 + (c & 1)*4096;
        const int halfsel = (c >> 1)*64;
        const int swzA = ((((c & 1)*4 + hi2) ^ r7) << 3);
        __builtin_amdgcn_s_setprio(1);
        {
          short8 af[4];
          #pragma unroll
          for (int mt = 0; mt < 4; ++mt)
            af[mt] = *(const short8*)&s_h[(size_t)(m_off + mt*16 + l15)*128 + halfsel + swzA];
          #pragma unroll
          for (int nt = 0; nt < 4; ++nt){
            const short8 bf = *(const short8*)&wb[(o_off + nt*16 + l15)*32 + swb];
            #pragma unroll
            for (int mt = 0; mt < 4; ++mt)
              oacc[mt][nt] = __builtin_amdgcn_mfma_f32_16x16x32_bf16(af[mt], bf, oacc[mt][nt], 0,0,0);
          }
        }
        __builtin_amdgcn_s_setprio(0);
        LGKM0();                            // ds_reads retired
        BAR();                              // -> chunk buffer reusable
      }
    }
  }

  // ---- output: device-scope fp32 atomics (4 expert-group blocks per tile) ----
  #pragma unroll
  for (int mt = 0; mt < 4; ++mt)
    #pragma unroll
    for (int nt = 0; nt < 4; ++nt)
      #pragma unroll
      for (int r = 0; r < 4; ++r)
        atomicAdd(&out[(size_t)(blk_m0 + m_off + mt*16 + hi2*4 + r)*OUT_ + o_off + nt*16 + l15],
                  oacc[mt][nt][r]);
}

extern "C" void kernel_launch(void* const* d_in, const int* in_sizes, int n_in,
                              void* d_out, int out_size, void* d_ws, size_t ws_size,
                              hipStream_t stream){
  const float* x  = (const float*)d_in[0];
  const float* u  = (const float*)d_in[1];
  const float* dd = (const float*)d_in[2];
  const float* gW = (const float*)d_in[3];
  const float* gb = (const float*)d_in[4];
  const float* W1 = (const float*)d_in[5];
  const float* b1 = (const float*)d_in[6];
  const float* W2 = (const float*)d_in[7];
  const float* b2 = (const float*)d_in[8];
  float* out = (float*)d_out;

  short* xb  = (short*)d_ws;
  short* w1b = xb  + (size_t)B_*IN_;
  short* w2b = w1b + (size_t)E_*HID_*IN_;
  float* gw  = (float*)(w2b + (size_t)E_*OUT_*HID_);

  hipMemsetAsync(d_out, 0, (size_t)B_*OUT_*sizeof(float), stream);
  hipLaunchKernelGGL(convert_kernel, dim3(4096), dim3(256), 0, stream, x, W1, W2, xb, w1b, w2b);
  hipLaunchKernelGGL(gate_kernel, dim3(B_/64), dim3(256), 0, stream, u, xb, dd, gW, gb, gw);
  hipLaunchKernelGGL(moe_kernel, dim3(B_/128, 4), dim3(256), 0, stream, xb, w1b, w2b, gw, b1, b2, out);
  (void)in_sizes; (void)n_in; (void)out_size; (void)ws_size;
}

// Round 9
// 364.783 us; speedup vs baseline: 1.5653x; 1.5653x over previous
//
#include <hip/hip_runtime.h>

#define B_    32768
#define IN_   512
#define HID_  256
#define OUT_  128
#define E_    16
#define CTX_  256
#define DEMO_ 16
#define GIN_  784

typedef __attribute__((ext_vector_type(8))) short short8;   // 8 bf16 = 4 VGPRs
typedef __attribute__((ext_vector_type(4))) float floatx4;  // MFMA C/D

// fp32 -> bf16 round-to-nearest-even
__device__ __forceinline__ short f2bf(float x){
  unsigned u = __builtin_bit_cast(unsigned, x);
  u += 0x7FFFu + ((u >> 16) & 1u);
  return (short)(u >> 16);
}

__device__ __forceinline__ short8 pack8(float4 a, float4 b){
  short8 r;
  r[0]=f2bf(a.x); r[1]=f2bf(a.y); r[2]=f2bf(a.z); r[3]=f2bf(a.w);
  r[4]=f2bf(b.x); r[5]=f2bf(b.y); r[6]=f2bf(b.z); r[7]=f2bf(b.w);
  return r;
}

__device__ __forceinline__ void load_lds16(const short* g, short* l){
  __builtin_amdgcn_global_load_lds((const __attribute__((address_space(1))) void*)g,
                                   (__attribute__((address_space(3))) void*)l,
                                   16, 0, 0);
}

// Counted-waitcnt + raw-barrier discipline (T3+T4).
#define VMCNT8()  asm volatile("s_waitcnt vmcnt(8)"  ::: "memory")
#define VMCNT0()  asm volatile("s_waitcnt vmcnt(0)"  ::: "memory")
#define BAR() do{ asm volatile("" ::: "memory"); __builtin_amdgcn_s_barrier(); \
                  asm volatile("" ::: "memory"); }while(0)
// Retire this wave's LDS ops BEFORE signalling a buffer-reuse barrier.
#define LGKM0() do{ asm volatile("s_waitcnt lgkmcnt(0)" ::: "memory"); \
                    __builtin_amdgcn_sched_barrier(0); }while(0)

// Stage a 128x64 bf16 tile (16 KB) global->LDS with XOR-swizzle on the 16B
// column block. LDS[row][cb] = G[row][cb ^ (row&7)]; readers fetch (kb ^ (row&7)).
__device__ __forceinline__ void stage128x64(short* lds, const short* g, int gpitch, int tid){
  const int wvv = tid >> 6, ln = tid & 63;
  const int cb = ln & 7, rsub = ln >> 3;
  #pragma unroll
  for (int i = 0; i < 4; ++i){
    const int r0  = (wvv*4 + i)*8;           // wave-uniform row base
    const int row = r0 + rsub;
    const short* gp = g + (size_t)row*gpitch + ((cb ^ rsub) << 3);
    load_lds16(gp, lds + r0*64);             // lane writes base + lane*16B
  }
}

// ---------------- fp32 -> bf16 convert (W1, W2 only; x handled by gate) ----------------
__global__ void convert_kernel(const float* __restrict__ w1, const float* __restrict__ w2,
                               short* __restrict__ w1b, short* __restrict__ w2b){
  const int N2 = E_*HID_*IN_, N3 = E_*OUT_*HID_;
  const int total4 = (N2 + N3) >> 2;
  for (int i = blockIdx.x*blockDim.x + threadIdx.x; i < total4; i += gridDim.x*blockDim.x){
    int e4 = i << 2;
    const float* src; short* dst; int off;
    if (e4 < N2) { src = w1; dst = w1b; off = e4; }
    else         { src = w2; dst = w2b; off = e4 - N2; }
    float4 v = *(const float4*)(src + off);
    *(short4*)(dst + off) = make_short4(f2bf(v.x), f2bf(v.y), f2bf(v.z), f2bf(v.w));
  }
}

// ---------------- gate via MFMA + xb emission ----------------
// softmax(cat(u,x,d) @ gW^T + gb). Reads x as f32; the bf16 pack it already
// needs for the MFMA A-operand is stored to xb (each x element is covered by
// exactly one (row, t, quad) lane across the grid -> full single-write of xb,
// bit-identical to the old convert path since f2bf is shared).
__global__ __launch_bounds__(256)
void gate_kernel(const float* __restrict__ x, const float* __restrict__ u,
                 const float* __restrict__ d, const float* __restrict__ gW,
                 const float* __restrict__ gb, short* __restrict__ xb,
                 float* __restrict__ wout){
  const int tid  = threadIdx.x;
  const int wave = tid >> 6, lane = tid & 63;
  const int l15  = lane & 15, quad = lane >> 4;
  const int row0 = blockIdx.x*64 + wave*16;
  const int rA   = row0 + l15;
  const int kq   = quad*8;

  floatx4 acc  = {0.f,0.f,0.f,0.f};
  floatx4 acc2 = {0.f,0.f,0.f,0.f};

  // u segment (features 0..255)
  #pragma unroll
  for (int t = 0; t < 8; ++t){
    const float4 a0 = *(const float4*)&u[(size_t)rA*CTX_ + t*32 + kq];
    const float4 a1 = *(const float4*)&u[(size_t)rA*CTX_ + t*32 + kq + 4];
    const float4 b0 = *(const float4*)&gW[(size_t)l15*GIN_ + t*32 + kq];
    const float4 b1 = *(const float4*)&gW[(size_t)l15*GIN_ + t*32 + kq + 4];
    acc = __builtin_amdgcn_mfma_f32_16x16x32_bf16(pack8(a0,a1), pack8(b0,b1), acc, 0,0,0);
  }
  // x segment (features 256..767): f32 load, pack once, feed MFMA AND store xb
  #pragma unroll
  for (int t = 0; t < 16; ++t){
    const float4 a0 = *(const float4*)&x[(size_t)rA*IN_ + t*32 + kq];
    const float4 a1 = *(const float4*)&x[(size_t)rA*IN_ + t*32 + kq + 4];
    const short8 af = pack8(a0, a1);
    *(short8*)&xb[(size_t)rA*IN_ + t*32 + kq] = af;    // 16B aligned (kq mult of 8)
    const float4 b0 = *(const float4*)&gW[(size_t)l15*GIN_ + 256 + t*32 + kq];
    const float4 b1 = *(const float4*)&gW[(size_t)l15*GIN_ + 256 + t*32 + kq + 4];
    acc2 = __builtin_amdgcn_mfma_f32_16x16x32_bf16(af, pack8(b0,b1), acc2, 0,0,0);
  }
  // d segment (features 768..783): zero-pad K to 32
  {
    short8 af = {0,0,0,0,0,0,0,0}, bf = {0,0,0,0,0,0,0,0};
    if (quad < 2){
      const float4 a0 = *(const float4*)&d[(size_t)rA*DEMO_ + kq];
      const float4 a1 = *(const float4*)&d[(size_t)rA*DEMO_ + kq + 4];
      const float4 b0 = *(const float4*)&gW[(size_t)l15*GIN_ + 768 + kq];
      const float4 b1 = *(const float4*)&gW[(size_t)l15*GIN_ + 768 + kq + 4];
      af = pack8(a0,a1); bf = pack8(b0,b1);
    }
    acc = __builtin_amdgcn_mfma_f32_16x16x32_bf16(af, bf, acc, 0,0,0);
  }

  const float bias = gb[l15];
  #pragma unroll
  for (int r = 0; r < 4; ++r){
    float v = acc[r] + acc2[r] + bias;
    float m = v;
    #pragma unroll
    for (int s = 1; s <= 8; s <<= 1) m = fmaxf(m, __shfl_xor(m, s));
    const float p = __expf(v - m);
    float ssum = p;
    #pragma unroll
    for (int s = 1; s <= 8; s <<= 1) ssum += __shfl_xor(ssum, s);
    wout[(size_t)(row0 + quad*4 + r)*E_ + l15] = p / ssum;
  }
}

// ---------------- fused MoE (verbatim R4 structure, 230.5 us verified) ----------------
// K=64 chunks, dbuf, counted vmcnt distance-1:
//   stage(kc+1) -> vmcnt(8) [retires exactly stage(kc); stage(kc+1)'s 8 loads
//   stay in flight across both barriers] -> s_barrier -> 32 MFMA -> lgkm0 ->
//   s_barrier.
// LDS 64 KB:
//   buf0 [0,32768):      x tile [0,16K) | w1 tile [16K,32K)
//   buf1 [32768,65536):  x tile | w1 tile
//   s_h  [0,32768):      [128][128] block-XOR-swizzled (aliases buf0)
//   s_w2 [32768,65536):  2 x [128][64] chunks (aliases buf1)
__global__ __launch_bounds__(256, 2)
void moe_kernel(const short* __restrict__ xb, const short* __restrict__ w1b,
                const short* __restrict__ w2b, const float* __restrict__ gatew,
                const float* __restrict__ b1g, const float* __restrict__ b2g,
                float* __restrict__ out){
  __shared__ alignas(16) char smem[65536];
  short* s_h  = (short*)smem;
  short* s_w2 = (short*)(smem + 32768);

  const int tid  = threadIdx.x;
  const int wv   = tid >> 6;
  const int lane = tid & 63;
  const int l15  = lane & 15;
  const int hi2  = lane >> 4;
  const int r7   = l15 & 7;
  const int h_off  = (wv >> 1) * 64;      // GEMM1: A rows (hidden)
  const int mb_off = (wv & 1) * 64;       // GEMM1: B cols (batch)
  const int m_off  = (wv >> 1) * 64;      // GEMM2: rows (batch)
  const int o_off  = (wv & 1) * 64;       // GEMM2: cols (out)
  const int blk_m0 = blockIdx.x * 128;
  const int eg = blockIdx.y;              // expert group 0..3

  floatx4 oacc[4][4];
  #pragma unroll
  for (int a = 0; a < 4; ++a)
    #pragma unroll
    for (int b = 0; b < 4; ++b) oacc[a][b] = floatx4{0.f,0.f,0.f,0.f};

  // bias-2 term for THIS block's 4 experts (linear over e -> distributable)
  #pragma unroll 1
  for (int ei = 0; ei < 4; ++ei){
    const int e = eg*4 + ei;
    float b2v[4];
    #pragma unroll
    for (int nt = 0; nt < 4; ++nt) b2v[nt] = b2g[e*OUT_ + o_off + nt*16 + l15];
    #pragma unroll
    for (int mt = 0; mt < 4; ++mt){
      #pragma unroll
      for (int r = 0; r < 4; ++r){
        const float wgt = gatew[(size_t)(blk_m0 + m_off + mt*16 + hi2*4 + r)*E_ + e];
        #pragma unroll
        for (int nt = 0; nt < 4; ++nt) oacc[mt][nt][r] += wgt * b2v[nt];
      }
    }
  }

  const short* xbase = xb + (size_t)blk_m0*IN_;

  #pragma unroll 1
  for (int ei = 0; ei < 4; ++ei){
    const int e = eg*4 + ei;
    #pragma unroll 1
    for (int half = 0; half < 2; ++half){
      const short* w1base = w1b + (size_t)(e*HID_ + half*128) * IN_;
      const short* w2base = w2b + (size_t)e*OUT_*HID_ + half*128;

      floatx4 g1[4][4];
      #pragma unroll
      for (int a = 0; a < 4; ++a)
        #pragma unroll
        for (int b = 0; b < 4; ++b) g1[a][b] = floatx4{0.f,0.f,0.f,0.f};

      // ---- GEMM1 prologue: stage chunk 0 into buf0 (prev LGKM0+BAR made it safe)
      stage128x64((short*)(smem +      0), xbase,  IN_, tid);
      stage128x64((short*)(smem + 16384), w1base, IN_, tid);

      // ---- GEMM1 main loop: counted vmcnt, distance-1 prefetch
      #pragma unroll 1
      for (int kc = 0; kc < 8; ++kc){
        if (kc < 7){
          char* nb = smem + ((kc + 1) & 1)*32768;
          stage128x64((short*)nb,            xbase  + (kc+1)*64, IN_, tid);
          stage128x64((short*)(nb + 16384),  w1base + (kc+1)*64, IN_, tid);
          VMCNT8();                         // head of queue = stage(kc) -> retired
        } else {
          VMCNT0();                         // last chunk: drain
        }
        BAR();                              // all waves' stage(kc) landed
        const short* buf = (const short*)(smem + (kc & 1)*32768);
        __builtin_amdgcn_s_setprio(1);
        #pragma unroll
        for (int ks = 0; ks < 2; ++ks){
          const int kb  = ks*4 + hi2;
          const int swz = (kb ^ r7) << 3;
          short8 af[4], bf[4];
          #pragma unroll
          for (int ht = 0; ht < 4; ++ht)
            af[ht] = *(const short8*)&buf[8192 + (h_off + ht*16 + l15)*64 + swz];
          #pragma unroll
          for (int mt = 0; mt < 4; ++mt)
            bf[mt] = *(const short8*)&buf[(mb_off + mt*16 + l15)*64 + swz];
          #pragma unroll
          for (int ht = 0; ht < 4; ++ht)
            #pragma unroll
            for (int mt = 0; mt < 4; ++mt)
              g1[ht][mt] = __builtin_amdgcn_mfma_f32_16x16x32_bf16(af[ht], bf[mt], g1[ht][mt], 0,0,0);
        }
        __builtin_amdgcn_s_setprio(0);
        LGKM0();                            // this wave's ds_reads retired
        BAR();                              // -> buf safely reusable
      }

      // ---- stage W2 (2 x 16 KB) into buf1 region; overlaps the epilogue VALU.
      stage128x64(s_w2,        w2base,      HID_, tid);
      stage128x64(s_w2 + 8192, w2base + 64, HID_, tid);

      // ---- epilogue: relu(+b1)*gate -> bf16 -> s_h (block-XOR swizzled) ----
      {
        float4 b1v[4];
        #pragma unroll
        for (int ht = 0; ht < 4; ++ht)
          b1v[ht] = *(const float4*)&b1g[e*HID_ + half*128 + h_off + ht*16 + hi2*4];
        float wgt[4];
        #pragma unroll
        for (int mt = 0; mt < 4; ++mt)
          wgt[mt] = gatew[(size_t)(blk_m0 + mb_off + mt*16 + l15)*E_ + e];
        #pragma unroll
        for (int ht = 0; ht < 4; ++ht){
          const float b1r[4] = {b1v[ht].x, b1v[ht].y, b1v[ht].z, b1v[ht].w};
          const int hb3 = 2*ht + (hi2 >> 1);          // 16B-block idx (low 3 bits)
          #pragma unroll
          for (int mt = 0; mt < 4; ++mt){
            short4 pk;
            float v0 = fmaxf(g1[ht][mt][0] + b1r[0], 0.f) * wgt[mt];
            float v1 = fmaxf(g1[ht][mt][1] + b1r[1], 0.f) * wgt[mt];
            float v2 = fmaxf(g1[ht][mt][2] + b1r[2], 0.f) * wgt[mt];
            float v3 = fmaxf(g1[ht][mt][3] + b1r[3], 0.f) * wgt[mt];
            pk.x = f2bf(v0); pk.y = f2bf(v1); pk.z = f2bf(v2); pk.w = f2bf(v3);
            *(short4*)&s_h[(size_t)(mb_off + mt*16 + l15)*128 + h_off
                           + ((hb3 ^ r7) << 3) + (hi2 & 1)*4] = pk;
          }
        }
      }
      asm volatile("s_waitcnt vmcnt(0) lgkmcnt(0)" ::: "memory");  // W2 DMA + s_h done
      __builtin_amdgcn_sched_barrier(0);
      BAR();

      // ---- GEMM2: oacc += H[128,128] @ W2_e[:,half]^T — barrier-free ----
      __builtin_amdgcn_s_setprio(1);
      #pragma unroll
      for (int kc2 = 0; kc2 < 2; ++kc2){
        const short* wb = s_w2 + kc2*8192;
        #pragma unroll
        for (int ks = 0; ks < 2; ++ks){
          const int kb  = ks*4 + hi2;
          const int swz = (kb ^ r7) << 3;
          short8 af[4], bf[4];
          #pragma unroll
          for (int mt = 0; mt < 4; ++mt)
            af[mt] = *(const short8*)&s_h[(size_t)(m_off + mt*16 + l15)*128 + kc2*64 + swz];
          #pragma unroll
          for (int nt = 0; nt < 4; ++nt)
            bf[nt] = *(const short8*)&wb[(o_off + nt*16 + l15)*64 + swz];
          #pragma unroll
          for (int mt = 0; mt < 4; ++mt)
            #pragma unroll
            for (int nt = 0; nt < 4; ++nt)
              oacc[mt][nt] = __builtin_amdgcn_mfma_f32_16x16x32_bf16(af[mt], bf[nt], oacc[mt][nt], 0,0,0);
        }
      }
      __builtin_amdgcn_s_setprio(0);
      LGKM0();                              // GEMM2 ds_reads retired
      BAR();                                // -> s_h/s_w2 region reusable
    }
  }

  // ---- output: device-scope fp32 atomics (4 expert-group blocks per tile) ----
  #pragma unroll
  for (int mt = 0; mt < 4; ++mt)
    #pragma unroll
    for (int nt = 0; nt < 4; ++nt)
      #pragma unroll
      for (int r = 0; r < 4; ++r)
        atomicAdd(&out[(size_t)(blk_m0 + m_off + mt*16 + hi2*4 + r)*OUT_ + o_off + nt*16 + l15],
                  oacc[mt][nt][r]);
}

extern "C" void kernel_launch(void* const* d_in, const int* in_sizes, int n_in,
                              void* d_out, int out_size, void* d_ws, size_t ws_size,
                              hipStream_t stream){
  const float* x  = (const float*)d_in[0];
  const float* u  = (const float*)d_in[1];
  const float* dd = (const float*)d_in[2];
  const float* gW = (const float*)d_in[3];
  const float* gb = (const float*)d_in[4];
  const float* W1 = (const float*)d_in[5];
  const float* b1 = (const float*)d_in[6];
  const float* W2 = (const float*)d_in[7];
  const float* b2 = (const float*)d_in[8];
  float* out = (float*)d_out;

  short* xb  = (short*)d_ws;
  short* w1b = xb  + (size_t)B_*IN_;
  short* w2b = w1b + (size_t)E_*HID_*IN_;
  float* gw  = (float*)(w2b + (size_t)E_*OUT_*HID_);

  hipMemsetAsync(d_out, 0, (size_t)B_*OUT_*sizeof(float), stream);
  hipLaunchKernelGGL(convert_kernel, dim3(1024), dim3(256), 0, stream, W1, W2, w1b, w2b);
  hipLaunchKernelGGL(gate_kernel, dim3(B_/64), dim3(256), 0, stream, x, u, dd, gW, gb, xb, gw);
  hipLaunchKernelGGL(moe_kernel, dim3(B_/128, 4), dim3(256), 0, stream,
                     xb, w1b, w2b, gw, b1, b2, out);
  (void)in_sizes; (void)n_in; (void)out_size; (void)ws_size;
}